// Round 2
// baseline (648.507 us; speedup 1.0000x reference)
//
#include <hip/hip_runtime.h>
#include <stdint.h>
#include <stddef.h>

typedef int v4i __attribute__((ext_vector_type(4)));

#define GELU_A   (-0.2888f)
#define GELU_B   (-1.769f)
#define INV_SQRT2 0.70710678118654752440f

// ---- order-preserving float<->uint encoding for atomic min/max ----
__device__ __forceinline__ unsigned enc_f(float f){
  unsigned u = __float_as_uint(f);
  return (u & 0x80000000u) ? ~u : (u | 0x80000000u);
}
__device__ __forceinline__ float dec_f(unsigned e){
  unsigned u = (e & 0x80000000u) ? (e & 0x7FFFFFFFu) : ~e;
  return __uint_as_float(u);
}

__device__ __forceinline__ float int_gelu_f(float x){
  float t = x * INV_SQRT2;
  float at = fminf(fabsf(t), 1.769f);
  float u = at + GELU_B;                 // in [-1.769, 0]
  float p = GELU_A * (u * u) + 1.0f;
  float L = (t > 0.0f) ? p : ((t < 0.0f) ? -p : 0.0f);
  return x * 0.5f * (1.0f + L);
}

// scalar slots: 0 enc(xmin), 1 enc(xmax), 2 bits(absmax w1), 3 bits(absmax w2),
//               4 enc(gmin), 5 enc(gmax)
__global__ void init_scalars(unsigned* sc){
  if (threadIdx.x == 0){
    sc[0] = 0xFFFFFFFFu;
    sc[1] = 0u;
    sc[2] = 0u;
    sc[3] = 0u;
    sc[4] = 0xFFFFFFFFu;
    sc[5] = 0u;
  }
}

// blocks [0,512): x min/max; [512,640): absmax w1 -> slot2; [640,768): absmax w2 -> slot3
__global__ __launch_bounds__(256) void reduce_stats(
    const float4* __restrict__ x, int nx4,
    const float4* __restrict__ w1, int n14,
    const float4* __restrict__ w2, int n24,
    unsigned* __restrict__ sc)
{
  __shared__ float ra[256], rb[256];
  const int tid = threadIdx.x;
  const int b = blockIdx.x;
  if (b < 512){
    float lmin = 3.4e38f, lmax = -3.4e38f;
    for (long i = (long)b * 256 + tid; i < nx4; i += 512L * 256L){
      float4 v = x[i];
      lmin = fminf(lmin, fminf(fminf(v.x, v.y), fminf(v.z, v.w)));
      lmax = fmaxf(lmax, fmaxf(fmaxf(v.x, v.y), fmaxf(v.z, v.w)));
    }
    ra[tid] = lmin; rb[tid] = lmax;
    __syncthreads();
    for (int s = 128; s > 0; s >>= 1){
      if (tid < s){ ra[tid] = fminf(ra[tid], ra[tid + s]); rb[tid] = fmaxf(rb[tid], rb[tid + s]); }
      __syncthreads();
    }
    if (tid == 0){
      atomicMin(&sc[0], enc_f(ra[0]));
      atomicMax(&sc[1], enc_f(rb[0]));
    }
  } else {
    const float4* w; int n4; int slot; int bl;
    if (b < 640){ w = w1; n4 = n14; slot = 2; bl = b - 512; }
    else        { w = w2; n4 = n24; slot = 3; bl = b - 640; }
    float la = 0.0f;
    for (long i = (long)bl * 256 + tid; i < n4; i += 128L * 256L){
      float4 v = w[i];
      la = fmaxf(la, fmaxf(fmaxf(fabsf(v.x), fabsf(v.y)), fmaxf(fabsf(v.z), fabsf(v.w))));
    }
    ra[tid] = la;
    __syncthreads();
    for (int s = 128; s > 0; s >>= 1){
      if (tid < s) ra[tid] = fmaxf(ra[tid], ra[tid + s]);
      __syncthreads();
    }
    if (tid == 0) atomicMax(&sc[slot], __float_as_uint(ra[0]));
  }
}

// per-tensor asymmetric uint8 fake-quant of activations, stored as (q-128) int8
__global__ __launch_bounds__(256) void quant_act(
    const float4* __restrict__ in, unsigned* __restrict__ out, long n4,
    const unsigned* __restrict__ sc, int slot)
{
  const float vmin = dec_f(sc[slot]);
  const float vmax = dec_f(sc[slot + 1]);
  const float s  = fmaxf(vmax - vmin, 1e-8f) / 255.0f;
  const float zp = rintf(-vmin / s);
  const long stride = (long)gridDim.x * blockDim.x;
  for (long i = (long)blockIdx.x * blockDim.x + threadIdx.x; i < n4; i += stride){
    float4 v = in[i];
    int q0 = (int)fminf(fmaxf(rintf(v.x / s) + zp, 0.0f), 255.0f) - 128;
    int q1 = (int)fminf(fmaxf(rintf(v.y / s) + zp, 0.0f), 255.0f) - 128;
    int q2 = (int)fminf(fmaxf(rintf(v.z / s) + zp, 0.0f), 255.0f) - 128;
    int q3 = (int)fminf(fmaxf(rintf(v.w / s) + zp, 0.0f), 255.0f) - 128;
    out[i] = ((unsigned)(q0 & 255)) | ((unsigned)(q1 & 255) << 8) |
             ((unsigned)(q2 & 255) << 16) | ((unsigned)(q3 & 255) << 24);
  }
}

// per-tensor symmetric int8 weight fake-quant; one block per row; also row sums
__global__ __launch_bounds__(256) void quant_w(
    const float* __restrict__ w1, const float* __restrict__ w2,
    int8_t* __restrict__ qw1, int8_t* __restrict__ qw2,
    int* __restrict__ rs1, int* __restrict__ rs2,
    const unsigned* __restrict__ sc, int n1, int k1, int k2)
{
  __shared__ int red[256];
  const int b = blockIdx.x, tid = threadIdx.x;
  const float* w; int8_t* q; int* rs; int K; int n; float s;
  if (b < n1){ w = w1; q = qw1; rs = rs1; K = k1; n = b;
               s = fmaxf(__uint_as_float(sc[2]), 1e-8f) / 127.0f; }
  else       { w = w2; q = qw2; rs = rs2; K = k2; n = b - n1;
               s = fmaxf(__uint_as_float(sc[3]), 1e-8f) / 127.0f; }
  int sum = 0;
  for (int k = tid; k < K; k += 256){
    float v = w[(size_t)n * K + k];
    float qf = fminf(fmaxf(rintf(v / s), -128.0f), 127.0f);
    int qi = (int)qf;
    q[(size_t)n * K + k] = (int8_t)qi;
    sum += qi;
  }
  red[tid] = sum;
  __syncthreads();
  for (int st = 128; st > 0; st >>= 1){
    if (tid < st) red[tid] += red[tid + st];
    __syncthreads();
  }
  if (tid == 0) rs[n] = red[0];
}

// MODE 0: h->gelu-> g min/max atomics only (no store)
// MODE 2: h->gelu-> quantize with g stats -> store int8 (q-128)
// MODE 1: h + bias -> store fp32 out
//
// Weights-resident structure: B-slab (128 n-rows x 384 k) staged in LDS once
// per slab (2 barriers per 96 MFMAs); A fragments streamed directly
// global->VGPR (16 rows x 64B cache lines, L2/L3-hot). Barrier-free inner
// K-loop -> compiler can hoist A loads arbitrarily far ahead.
// LDS row stride 400B (=100 banks === 4 mod 32): every 8-lane phase of
// ds_read_b128 / ds_write_b128 hits 8 distinct bank groups -> conflict-free.
// 50KB LDS -> 3 blocks/CU (12 waves) for latency hiding.
template<int MODE>
__global__ __launch_bounds__(256, 3) void gemm_i8(
    const int8_t* __restrict__ A, const int8_t* __restrict__ Bm,
    const int* __restrict__ rowsum, const float* __restrict__ bias,
    void* __restrict__ Cout, int M, int N, int K,
    unsigned* __restrict__ sc)
{
  constexpr int KSLAB = 384;
  constexpr int LSTR  = 400;                 // 384 data + 16 pad
  __shared__ __align__(16) int8_t ldsB[128 * LSTR];   // 51200 B

  const int tid  = threadIdx.x;
  const int lane = tid & 63;
  const int wave = tid >> 6;
  const int n0   = blockIdx.x * 128;
  const int m0   = blockIdx.y * 128;
  const int m16  = lane & 15;
  const int quad = lane >> 4;
  const int wm   = (wave & 1) * 64;
  const int wn   = (wave >> 1) * 64;

  // direct-from-global A fragment pointers (row-clamped for the M tail)
  const int8_t* aptr[4];
#pragma unroll
  for (int i = 0; i < 4; i++){
    int mr = m0 + wm + i * 16 + m16;
    if (mr >= M) mr = M - 1;
    aptr[i] = A + (size_t)mr * K + quad * 16;
  }

  v4i acc[4][4] = {};

  const int nslabs = K / KSLAB;
  for (int s = 0; s < nslabs; s++){
    const int ks = s * KSLAB;
    // preload slab to regs (issues while other waves finish previous slab)
    uint4 breg[12];
#pragma unroll
    for (int t = 0; t < 12; t++){
      int idx = tid + t * 256;
      int r = idx / 24, c = idx - r * 24;
      breg[t] = *(const uint4*)(Bm + (size_t)(n0 + r) * K + ks + c * 16);
    }
    __syncthreads();   // all waves done READING previous slab
#pragma unroll
    for (int t = 0; t < 12; t++){
      int idx = tid + t * 256;
      int r = idx / 24, c = idx - r * 24;
      *(uint4*)(ldsB + r * LSTR + c * 16) = breg[t];
    }
    __syncthreads();
    // barrier-free inner K-loop
#pragma unroll
    for (int kk = 0; kk < KSLAB; kk += 64){
      v4i af[4], bf[4];
#pragma unroll
      for (int j = 0; j < 4; j++)
        bf[j] = *(const v4i*)(ldsB + (wn + j * 16 + m16) * LSTR + kk + quad * 16);
#pragma unroll
      for (int i = 0; i < 4; i++)
        af[i] = *(const v4i*)(aptr[i] + ks + kk);
#pragma unroll
      for (int i = 0; i < 4; i++)
#pragma unroll
        for (int j = 0; j < 4; j++)
          acc[i][j] = __builtin_amdgcn_mfma_i32_16x16x64_i8(af[i], bf[j], acc[i][j], 0, 0, 0);
    }
  }

  // epilogue scalars
  float s_h, off_h;
  if constexpr (MODE == 1){
    float gmin = dec_f(sc[4]), gmax = dec_f(sc[5]);
    float sg = fmaxf(gmax - gmin, 1e-8f) / 255.0f;
    float zp = rintf(-gmin / sg);
    float sw = fmaxf(__uint_as_float(sc[3]), 1e-8f) / 127.0f;
    s_h = sg * sw; off_h = 128.0f - zp;
  } else {
    float xmin = dec_f(sc[0]), xmax = dec_f(sc[1]);
    float sx = fmaxf(xmax - xmin, 1e-8f) / 255.0f;
    float zp = rintf(-xmin / sx);
    float sw = fmaxf(__uint_as_float(sc[2]), 1e-8f) / 127.0f;
    s_h = sx * sw; off_h = 128.0f - zp;
  }
  float qs = 1.0f, qzp = 0.0f;
  if constexpr (MODE == 2){
    float gmin = dec_f(sc[4]), gmax = dec_f(sc[5]);
    qs = fmaxf(gmax - gmin, 1e-8f) / 255.0f;
    qzp = rintf(-gmin / qs);
  }

  float lmin = 3.4e38f, lmax = -3.4e38f;
#pragma unroll
  for (int j = 0; j < 4; j++){
    const int n = n0 + wn + j * 16 + m16;
    const float rsv = off_h * (float)rowsum[n];
    const float bv = bias[n];
#pragma unroll
    for (int i = 0; i < 4; i++){
      const int mbase = m0 + wm + i * 16 + quad * 4;
#pragma unroll
      for (int r = 0; r < 4; r++){
        const int m = mbase + r;
        if (m < M){
          float h = s_h * ((float)acc[i][j][r] + rsv) + bv;
          if constexpr (MODE == 0){
            float gv = int_gelu_f(h);
            lmin = fminf(lmin, gv); lmax = fmaxf(lmax, gv);
          } else if constexpr (MODE == 2){
            float gv = int_gelu_f(h);
            float qf = fminf(fmaxf(rintf(gv / qs) + qzp, 0.0f), 255.0f);
            ((int8_t*)Cout)[(size_t)m * N + n] = (int8_t)((int)qf - 128);
          } else {
            ((float*)Cout)[(size_t)m * N + n] = h;
          }
        }
      }
    }
  }

  if constexpr (MODE == 0){
    __syncthreads();                       // ldsB reads all done; reuse as scratch
    float* redA = (float*)ldsB;
    float* redB = ((float*)ldsB) + 256;
    redA[tid] = lmin; redB[tid] = lmax;
    __syncthreads();
    for (int st = 128; st > 0; st >>= 1){
      if (tid < st){
        redA[tid] = fminf(redA[tid], redA[tid + st]);
        redB[tid] = fmaxf(redB[tid], redB[tid + st]);
      }
      __syncthreads();
    }
    if (tid == 0){
      atomicMin(&sc[4], enc_f(redA[0]));
      atomicMax(&sc[5], enc_f(redB[0]));
    }
  }
}

extern "C" void kernel_launch(void* const* d_in, const int* in_sizes, int n_in,
                              void* d_out, int out_size, void* d_ws, size_t ws_size,
                              hipStream_t stream)
{
  const float* x  = (const float*)d_in[0];
  const float* w1 = (const float*)d_in[1];
  const float* b1 = (const float*)d_in[2];
  const float* w2 = (const float*)d_in[3];
  const float* b2 = (const float*)d_in[4];
  float* out = (float*)d_out;

  const int H = in_sizes[2];            // 3072
  const int D = in_sizes[4];            // 768
  const int M = in_sizes[0] / D;        // 12608

  char* ws = (char*)d_ws;
  unsigned* sc = (unsigned*)ws;
  size_t off = 256;
  int8_t* qx  = (int8_t*)(ws + off); off += (size_t)M * D;   // 9.68 MB
  int8_t* qw1 = (int8_t*)(ws + off); off += (size_t)H * D;   // 2.36 MB
  int8_t* qw2 = (int8_t*)(ws + off); off += (size_t)D * H;   // 2.36 MB
  int* rs1 = (int*)(ws + off); off += (size_t)H * 4;
  int* rs2 = (int*)(ws + off); off += 4096;
  int8_t* qg  = (int8_t*)(ws + off); off += (size_t)M * H;   // 38.7 MB
  (void)ws_size; (void)n_in; (void)out_size;

  init_scalars<<<dim3(1), dim3(64), 0, stream>>>(sc);

  reduce_stats<<<dim3(768), dim3(256), 0, stream>>>(
      (const float4*)x, M * D / 4,
      (const float4*)w1, H * D / 4,
      (const float4*)w2, D * H / 4, sc);

  quant_act<<<dim3(1024), dim3(256), 0, stream>>>(
      (const float4*)x, (unsigned*)qx, (long)M * D / 4, sc, 0);

  quant_w<<<dim3(H + D), dim3(256), 0, stream>>>(
      w1, w2, qw1, qw2, rs1, rs2, sc, H, D, H);

  // GEMM1 pass A: g min/max only
  gemm_i8<0><<<dim3(H / 128, (M + 127) / 128), dim3(256), 0, stream>>>(
      qx, qw1, rs1, b1, nullptr, M, H, D, sc);

  // GEMM1 pass B: recompute, quantize g -> qg (int8, q-128)
  gemm_i8<2><<<dim3(H / 128, (M + 127) / 128), dim3(256), 0, stream>>>(
      qx, qw1, rs1, b1, qg, M, H, D, sc);

  // GEMM2: out = qg @ qw2^T + b2
  gemm_i8<1><<<dim3(D / 128, (M + 127) / 128), dim3(256), 0, stream>>>(
      qg, qw2, rs2, b2, out, M, D, H, sc);
}

// Round 3
// 413.130 us; speedup vs baseline: 1.5697x; 1.5697x over previous
//
#include <hip/hip_runtime.h>
#include <stdint.h>
#include <stddef.h>

typedef int v4i  __attribute__((ext_vector_type(4)));
typedef int v16i __attribute__((ext_vector_type(16)));

#define GELU_A   (-0.2888f)
#define GELU_B   (-1.769f)
#define INV_SQRT2 0.70710678118654752440f

// async 16B global->LDS (lane i's 16B lands at ldsbase + i*16; ldsbase wave-uniform)
#define GLD16(gp, lp) __builtin_amdgcn_global_load_lds( \
    (const __attribute__((address_space(1))) unsigned int*)(gp), \
    (__attribute__((address_space(3))) unsigned int*)(lp), 16, 0, 0)

// ---- order-preserving float<->uint encoding for atomic min/max ----
__device__ __forceinline__ unsigned enc_f(float f){
  unsigned u = __float_as_uint(f);
  return (u & 0x80000000u) ? ~u : (u | 0x80000000u);
}
__device__ __forceinline__ float dec_f(unsigned e){
  unsigned u = (e & 0x80000000u) ? (e & 0x7FFFFFFFu) : ~e;
  return __uint_as_float(u);
}

__device__ __forceinline__ float int_gelu_f(float x){
  float t = x * INV_SQRT2;
  float at = fminf(fabsf(t), 1.769f);
  float u = at + GELU_B;                 // in [-1.769, 0]
  float p = GELU_A * (u * u) + 1.0f;
  float L = (t > 0.0f) ? p : ((t < 0.0f) ? -p : 0.0f);
  return x * 0.5f * (1.0f + L);
}

// scalar slots: 0 enc(xmin), 1 enc(xmax), 2 bits(absmax w1), 3 bits(absmax w2),
//               4 enc(gmin), 5 enc(gmax)
__global__ void init_scalars(unsigned* sc){
  if (threadIdx.x == 0){
    sc[0] = 0xFFFFFFFFu;
    sc[1] = 0u;
    sc[2] = 0u;
    sc[3] = 0u;
    sc[4] = 0xFFFFFFFFu;
    sc[5] = 0u;
  }
}

// blocks [0,512): x min/max; [512,640): absmax w1 -> slot2; [640,768): absmax w2 -> slot3
__global__ __launch_bounds__(256) void reduce_stats(
    const float4* __restrict__ x, int nx4,
    const float4* __restrict__ w1, int n14,
    const float4* __restrict__ w2, int n24,
    unsigned* __restrict__ sc)
{
  __shared__ float ra[256], rb[256];
  const int tid = threadIdx.x;
  const int b = blockIdx.x;
  if (b < 512){
    float lmin = 3.4e38f, lmax = -3.4e38f;
    for (long i = (long)b * 256 + tid; i < nx4; i += 512L * 256L){
      float4 v = x[i];
      lmin = fminf(lmin, fminf(fminf(v.x, v.y), fminf(v.z, v.w)));
      lmax = fmaxf(lmax, fmaxf(fmaxf(v.x, v.y), fmaxf(v.z, v.w)));
    }
    ra[tid] = lmin; rb[tid] = lmax;
    __syncthreads();
    for (int s = 128; s > 0; s >>= 1){
      if (tid < s){ ra[tid] = fminf(ra[tid], ra[tid + s]); rb[tid] = fmaxf(rb[tid], rb[tid + s]); }
      __syncthreads();
    }
    if (tid == 0){
      atomicMin(&sc[0], enc_f(ra[0]));
      atomicMax(&sc[1], enc_f(rb[0]));
    }
  } else {
    const float4* w; int n4; int slot; int bl;
    if (b < 640){ w = w1; n4 = n14; slot = 2; bl = b - 512; }
    else        { w = w2; n4 = n24; slot = 3; bl = b - 640; }
    float la = 0.0f;
    for (long i = (long)bl * 256 + tid; i < n4; i += 128L * 256L){
      float4 v = w[i];
      la = fmaxf(la, fmaxf(fmaxf(fabsf(v.x), fabsf(v.y)), fmaxf(fabsf(v.z), fabsf(v.w))));
    }
    ra[tid] = la;
    __syncthreads();
    for (int s = 128; s > 0; s >>= 1){
      if (tid < s) ra[tid] = fmaxf(ra[tid], ra[tid + s]);
      __syncthreads();
    }
    if (tid == 0) atomicMax(&sc[slot], __float_as_uint(ra[0]));
  }
}

// per-tensor asymmetric uint8 fake-quant of activations, stored as (q-128) int8
__global__ __launch_bounds__(256) void quant_act(
    const float4* __restrict__ in, unsigned* __restrict__ out, long n4,
    const unsigned* __restrict__ sc, int slot)
{
  const float vmin = dec_f(sc[slot]);
  const float vmax = dec_f(sc[slot + 1]);
  const float s  = fmaxf(vmax - vmin, 1e-8f) / 255.0f;
  const float zp = rintf(-vmin / s);
  const long stride = (long)gridDim.x * blockDim.x;
  for (long i = (long)blockIdx.x * blockDim.x + threadIdx.x; i < n4; i += stride){
    float4 v = in[i];
    int q0 = (int)fminf(fmaxf(rintf(v.x / s) + zp, 0.0f), 255.0f) - 128;
    int q1 = (int)fminf(fmaxf(rintf(v.y / s) + zp, 0.0f), 255.0f) - 128;
    int q2 = (int)fminf(fmaxf(rintf(v.z / s) + zp, 0.0f), 255.0f) - 128;
    int q3 = (int)fminf(fmaxf(rintf(v.w / s) + zp, 0.0f), 255.0f) - 128;
    out[i] = ((unsigned)(q0 & 255)) | ((unsigned)(q1 & 255) << 8) |
             ((unsigned)(q2 & 255) << 16) | ((unsigned)(q3 & 255) << 24);
  }
}

// per-tensor symmetric int8 weight fake-quant; one block per row; also row sums
__global__ __launch_bounds__(256) void quant_w(
    const float* __restrict__ w1, const float* __restrict__ w2,
    int8_t* __restrict__ qw1, int8_t* __restrict__ qw2,
    int* __restrict__ rs1, int* __restrict__ rs2,
    const unsigned* __restrict__ sc, int n1, int k1, int k2)
{
  __shared__ int red[256];
  const int b = blockIdx.x, tid = threadIdx.x;
  const float* w; int8_t* q; int* rs; int K; int n; float s;
  if (b < n1){ w = w1; q = qw1; rs = rs1; K = k1; n = b;
               s = fmaxf(__uint_as_float(sc[2]), 1e-8f) / 127.0f; }
  else       { w = w2; q = qw2; rs = rs2; K = k2; n = b - n1;
               s = fmaxf(__uint_as_float(sc[3]), 1e-8f) / 127.0f; }
  int sum = 0;
  for (int k = tid; k < K; k += 256){
    float v = w[(size_t)n * K + k];
    float qf = fminf(fmaxf(rintf(v / s), -128.0f), 127.0f);
    int qi = (int)qf;
    q[(size_t)n * K + k] = (int8_t)qi;
    sum += qi;
  }
  red[tid] = sum;
  __syncthreads();
  for (int st = 128; st > 0; st >>= 1){
    if (tid < st) red[tid] += red[tid + st];
    __syncthreads();
  }
  if (tid == 0) rs[n] = red[0];
}

// MODE 0: h->gelu-> g min/max atomics only (no store)
// MODE 2: h->gelu-> quantize with g stats -> store int8 (q-128)
// MODE 1: h + bias -> store fp32 out
//
// 128x128 tile, BK=128, mfma_i32_32x32x32_i8, 4 waves each 64x64 (2x2 of 32x32).
// Both A and B staged via global_load_lds(16B) into FRAGMENT-ORDER LDS:
// 16 blocks of 1KB per operand, block [kb][rb] holds sub-tile rows rb*32..+32,
// k kb*32..+32 in exact lane order (lane L -> row rb*32+(L&31), khalf L>>5).
// -> DMA writes are the natural wave-uniform-base+lane*16 pattern, and every
// ds_read_b128 fragment load is stride-1 contiguous (zero bank conflicts).
// 2 barriers per 32 MFMAs; 32KB LDS; no staging VGPRs (no spill).
template<int MODE>
__global__ __launch_bounds__(256) void gemm_i8(
    const int8_t* __restrict__ A, const int8_t* __restrict__ Bm,
    const int* __restrict__ rowsum, const float* __restrict__ bias,
    void* __restrict__ Cout, int M, int N, int K,
    unsigned* __restrict__ sc)
{
  __shared__ __align__(16) int8_t ldsA[16384];
  __shared__ __align__(16) int8_t ldsB[16384];

  const int tid  = threadIdx.x;
  const int lane = tid & 63;
  const int wave = tid >> 6;
  const int l31  = lane & 31;
  const int kh   = lane >> 5;          // 0/1 : k half within 32-k block
  const int n0   = blockIdx.x * 128;
  const int m0   = blockIdx.y * 128;
  const int wm   = (wave & 1) * 64;
  const int wn   = (wave >> 1) * 64;

  // per-lane staging source offsets; wave w stages k-block kb=w, row-blocks t=0..3
  size_t aoff[4], boff[4];
#pragma unroll
  for (int t = 0; t < 4; t++){
    int ra = m0 + t * 32 + l31; if (ra >= M) ra = M - 1;
    aoff[t] = (size_t)ra * K + kh * 16 + wave * 32;
    boff[t] = (size_t)(n0 + t * 32 + l31) * K + kh * 16 + wave * 32;
  }

  const int rbA = (wave & 1) * 2;      // row-block base for A fragments
  const int rbB = (wave >> 1) * 2;     // row-block base for B fragments

  v16i acc[2][2] = {};

  for (int k0 = 0; k0 < K; k0 += 128){
    __syncthreads();                   // all waves done reading previous tile
#pragma unroll
    for (int t = 0; t < 4; t++){
      GLD16(A  + aoff[t] + k0, ldsA + (wave * 4 + t) * 1024);
      GLD16(Bm + boff[t] + k0, ldsB + (wave * 4 + t) * 1024);
    }
    __syncthreads();                   // drains vmcnt -> tile ready
#pragma unroll
    for (int kk = 0; kk < 4; kk++){
      v4i af[2], bf[2];
#pragma unroll
      for (int mi = 0; mi < 2; mi++)
        af[mi] = *(const v4i*)(ldsA + (kk * 4 + rbA + mi) * 1024 + lane * 16);
#pragma unroll
      for (int nj = 0; nj < 2; nj++)
        bf[nj] = *(const v4i*)(ldsB + (kk * 4 + rbB + nj) * 1024 + lane * 16);
#pragma unroll
      for (int mi = 0; mi < 2; mi++)
#pragma unroll
        for (int nj = 0; nj < 2; nj++)
          acc[mi][nj] = __builtin_amdgcn_mfma_i32_32x32x32_i8(af[mi], bf[nj], acc[mi][nj], 0, 0, 0);
    }
  }

  // epilogue scalars
  float s_h, off_h;
  if constexpr (MODE == 1){
    float gmin = dec_f(sc[4]), gmax = dec_f(sc[5]);
    float sg = fmaxf(gmax - gmin, 1e-8f) / 255.0f;
    float zp = rintf(-gmin / sg);
    float sw = fmaxf(__uint_as_float(sc[3]), 1e-8f) / 127.0f;
    s_h = sg * sw; off_h = 128.0f - zp;
  } else {
    float xmin = dec_f(sc[0]), xmax = dec_f(sc[1]);
    float sx = fmaxf(xmax - xmin, 1e-8f) / 255.0f;
    float zp = rintf(-xmin / sx);
    float sw = fmaxf(__uint_as_float(sc[2]), 1e-8f) / 127.0f;
    s_h = sx * sw; off_h = 128.0f - zp;
  }
  float qs = 1.0f, qzp = 0.0f;
  if constexpr (MODE == 2){
    float gmin = dec_f(sc[4]), gmax = dec_f(sc[5]);
    qs = fmaxf(gmax - gmin, 1e-8f) / 255.0f;
    qzp = rintf(-gmin / qs);
  }

  // C/D 32x32 layout: col = lane&31, row = (reg&3) + 8*(reg>>2) + 4*(lane>>5)
  float lmin = 3.4e38f, lmax = -3.4e38f;
#pragma unroll
  for (int nj = 0; nj < 2; nj++){
    const int n = n0 + wn + nj * 32 + l31;
    const float rsv = off_h * (float)rowsum[n];
    const float bv = bias[n];
#pragma unroll
    for (int mi = 0; mi < 2; mi++){
      const int mbase = m0 + wm + mi * 32 + 4 * kh;
#pragma unroll
      for (int r = 0; r < 16; r++){
        const int m = mbase + (r & 3) + 8 * (r >> 2);
        if (m < M){
          float h = s_h * ((float)acc[mi][nj][r] + rsv) + bv;
          if constexpr (MODE == 0){
            float gv = int_gelu_f(h);
            lmin = fminf(lmin, gv); lmax = fmaxf(lmax, gv);
          } else if constexpr (MODE == 2){
            float gv = int_gelu_f(h);
            float qf = fminf(fmaxf(rintf(gv / qs) + qzp, 0.0f), 255.0f);
            ((int8_t*)Cout)[(size_t)m * N + n] = (int8_t)((int)qf - 128);
          } else {
            ((float*)Cout)[(size_t)m * N + n] = h;
          }
        }
      }
    }
  }

  if constexpr (MODE == 0){
    __syncthreads();                   // all waves done with LDS -> reuse as scratch
    float* redA = (float*)ldsA;
    float* redB = ((float*)ldsA) + 256;
    redA[tid] = lmin; redB[tid] = lmax;
    __syncthreads();
    for (int st = 128; st > 0; st >>= 1){
      if (tid < st){
        redA[tid] = fminf(redA[tid], redA[tid + st]);
        redB[tid] = fmaxf(redB[tid], redB[tid + st]);
      }
      __syncthreads();
    }
    if (tid == 0){
      atomicMin(&sc[4], enc_f(redA[0]));
      atomicMax(&sc[5], enc_f(redB[0]));
    }
  }
}

extern "C" void kernel_launch(void* const* d_in, const int* in_sizes, int n_in,
                              void* d_out, int out_size, void* d_ws, size_t ws_size,
                              hipStream_t stream)
{
  const float* x  = (const float*)d_in[0];
  const float* w1 = (const float*)d_in[1];
  const float* b1 = (const float*)d_in[2];
  const float* w2 = (const float*)d_in[3];
  const float* b2 = (const float*)d_in[4];
  float* out = (float*)d_out;

  const int H = in_sizes[2];            // 3072
  const int D = in_sizes[4];            // 768
  const int M = in_sizes[0] / D;        // 12608

  char* ws = (char*)d_ws;
  unsigned* sc = (unsigned*)ws;
  size_t off = 256;
  int8_t* qx  = (int8_t*)(ws + off); off += (size_t)M * D;   // 9.68 MB
  int8_t* qw1 = (int8_t*)(ws + off); off += (size_t)H * D;   // 2.36 MB
  int8_t* qw2 = (int8_t*)(ws + off); off += (size_t)D * H;   // 2.36 MB
  int* rs1 = (int*)(ws + off); off += (size_t)H * 4;
  int* rs2 = (int*)(ws + off); off += 4096;
  int8_t* qg  = (int8_t*)(ws + off); off += (size_t)M * H;   // 38.7 MB
  (void)ws_size; (void)n_in; (void)out_size;

  init_scalars<<<dim3(1), dim3(64), 0, stream>>>(sc);

  reduce_stats<<<dim3(768), dim3(256), 0, stream>>>(
      (const float4*)x, M * D / 4,
      (const float4*)w1, H * D / 4,
      (const float4*)w2, D * H / 4, sc);

  quant_act<<<dim3(1024), dim3(256), 0, stream>>>(
      (const float4*)x, (unsigned*)qx, (long)M * D / 4, sc, 0);

  quant_w<<<dim3(H + D), dim3(256), 0, stream>>>(
      w1, w2, qw1, qw2, rs1, rs2, sc, H, D, H);

  // GEMM1 pass A: g min/max only
  gemm_i8<0><<<dim3(H / 128, (M + 127) / 128), dim3(256), 0, stream>>>(
      qx, qw1, rs1, b1, nullptr, M, H, D, sc);

  // GEMM1 pass B: recompute, quantize g -> qg (int8, q-128)
  gemm_i8<2><<<dim3(H / 128, (M + 127) / 128), dim3(256), 0, stream>>>(
      qx, qw1, rs1, b1, qg, M, H, D, sc);

  // GEMM2: out = qg @ qw2^T + b2
  gemm_i8<1><<<dim3(D / 128, (M + 127) / 128), dim3(256), 0, stream>>>(
      qg, qw2, rs2, b2, out, M, D, H, sc);
}

// Round 4
// 376.081 us; speedup vs baseline: 1.7244x; 1.0985x over previous
//
#include <hip/hip_runtime.h>
#include <stdint.h>
#include <stddef.h>

typedef int v4i  __attribute__((ext_vector_type(4)));
typedef int v16i __attribute__((ext_vector_type(16)));

#define GELU_A   (-0.2888f)
#define GELU_B   (-1.769f)
#define INV_SQRT2 0.70710678118654752440f

// async 16B global->LDS (lane i's 16B lands at ldsbase + i*16; ldsbase wave-uniform)
#define GLD16(gp, lp) __builtin_amdgcn_global_load_lds( \
    (const __attribute__((address_space(1))) unsigned int*)(gp), \
    (__attribute__((address_space(3))) unsigned int*)(lp), 16, 0, 0)

// ---- order-preserving float<->uint encoding for atomic min/max ----
__device__ __forceinline__ unsigned enc_f(float f){
  unsigned u = __float_as_uint(f);
  return (u & 0x80000000u) ? ~u : (u | 0x80000000u);
}
__device__ __forceinline__ float dec_f(unsigned e){
  unsigned u = (e & 0x80000000u) ? (e & 0x7FFFFFFFu) : ~e;
  return __uint_as_float(u);
}

__device__ __forceinline__ float int_gelu_f(float x){
  float t = x * INV_SQRT2;
  float at = fminf(fabsf(t), 1.769f);
  float u = at + GELU_B;                 // in [-1.769, 0]
  float p = GELU_A * (u * u) + 1.0f;
  float L = (t > 0.0f) ? p : ((t < 0.0f) ? -p : 0.0f);
  return x * 0.5f * (1.0f + L);
}

// scalar slots: 0 enc(xmin), 1 enc(xmax), 2 bits(absmax w1), 3 bits(absmax w2),
//               4 enc(gmin), 5 enc(gmax)
__global__ void init_scalars(unsigned* sc){
  if (threadIdx.x == 0){
    sc[0] = 0xFFFFFFFFu;
    sc[1] = 0u;
    sc[2] = 0u;
    sc[3] = 0u;
    sc[4] = 0xFFFFFFFFu;
    sc[5] = 0u;
  }
}

// blocks [0,1024): x min/max; [1024,1152): absmax w1 -> slot2; [1152,1280): absmax w2 -> slot3
__global__ __launch_bounds__(256) void reduce_stats(
    const float4* __restrict__ x, int nx4,
    const float4* __restrict__ w1, int n14,
    const float4* __restrict__ w2, int n24,
    unsigned* __restrict__ sc)
{
  __shared__ float ra[256], rb[256];
  const int tid = threadIdx.x;
  const int b = blockIdx.x;
  if (b < 1024){
    float lmin = 3.4e38f, lmax = -3.4e38f;
    for (long i = (long)b * 256 + tid; i < nx4; i += 1024L * 256L){
      float4 v = x[i];
      lmin = fminf(lmin, fminf(fminf(v.x, v.y), fminf(v.z, v.w)));
      lmax = fmaxf(lmax, fmaxf(fmaxf(v.x, v.y), fmaxf(v.z, v.w)));
    }
    ra[tid] = lmin; rb[tid] = lmax;
    __syncthreads();
    for (int s = 128; s > 0; s >>= 1){
      if (tid < s){ ra[tid] = fminf(ra[tid], ra[tid + s]); rb[tid] = fmaxf(rb[tid], rb[tid + s]); }
      __syncthreads();
    }
    if (tid == 0){
      atomicMin(&sc[0], enc_f(ra[0]));
      atomicMax(&sc[1], enc_f(rb[0]));
    }
  } else {
    const float4* w; int n4; int slot; int bl;
    if (b < 1152){ w = w1; n4 = n14; slot = 2; bl = b - 1024; }
    else         { w = w2; n4 = n24; slot = 3; bl = b - 1152; }
    float la = 0.0f;
    for (long i = (long)bl * 256 + tid; i < n4; i += 128L * 256L){
      float4 v = w[i];
      la = fmaxf(la, fmaxf(fmaxf(fabsf(v.x), fabsf(v.y)), fmaxf(fabsf(v.z), fabsf(v.w))));
    }
    ra[tid] = la;
    __syncthreads();
    for (int s = 128; s > 0; s >>= 1){
      if (tid < s) ra[tid] = fmaxf(ra[tid], ra[tid + s]);
      __syncthreads();
    }
    if (tid == 0) atomicMax(&sc[slot], __float_as_uint(ra[0]));
  }
}

// per-tensor asymmetric uint8 fake-quant of activations, stored as (q-128) int8
__global__ __launch_bounds__(256) void quant_act(
    const float4* __restrict__ in, unsigned* __restrict__ out, long n4,
    const unsigned* __restrict__ sc, int slot)
{
  const float vmin = dec_f(sc[slot]);
  const float vmax = dec_f(sc[slot + 1]);
  const float s  = fmaxf(vmax - vmin, 1e-8f) / 255.0f;
  const float zp = rintf(-vmin / s);
  const long stride = (long)gridDim.x * blockDim.x;
  for (long i = (long)blockIdx.x * blockDim.x + threadIdx.x; i < n4; i += stride){
    float4 v = in[i];
    int q0 = (int)fminf(fmaxf(rintf(v.x / s) + zp, 0.0f), 255.0f) - 128;
    int q1 = (int)fminf(fmaxf(rintf(v.y / s) + zp, 0.0f), 255.0f) - 128;
    int q2 = (int)fminf(fmaxf(rintf(v.z / s) + zp, 0.0f), 255.0f) - 128;
    int q3 = (int)fminf(fmaxf(rintf(v.w / s) + zp, 0.0f), 255.0f) - 128;
    out[i] = ((unsigned)(q0 & 255)) | ((unsigned)(q1 & 255) << 8) |
             ((unsigned)(q2 & 255) << 16) | ((unsigned)(q3 & 255) << 24);
  }
}

// per-tensor symmetric int8 weight fake-quant; one block per row; also row sums
__global__ __launch_bounds__(256) void quant_w(
    const float* __restrict__ w1, const float* __restrict__ w2,
    int8_t* __restrict__ qw1, int8_t* __restrict__ qw2,
    int* __restrict__ rs1, int* __restrict__ rs2,
    const unsigned* __restrict__ sc, int n1, int k1, int k2)
{
  __shared__ int red[256];
  const int b = blockIdx.x, tid = threadIdx.x;
  const float* w; int8_t* q; int* rs; int K; int n; float s;
  if (b < n1){ w = w1; q = qw1; rs = rs1; K = k1; n = b;
               s = fmaxf(__uint_as_float(sc[2]), 1e-8f) / 127.0f; }
  else       { w = w2; q = qw2; rs = rs2; K = k2; n = b - n1;
               s = fmaxf(__uint_as_float(sc[3]), 1e-8f) / 127.0f; }
  int sum = 0;
  for (int k = tid; k < K; k += 256){
    float v = w[(size_t)n * K + k];
    float qf = fminf(fmaxf(rintf(v / s), -128.0f), 127.0f);
    int qi = (int)qf;
    q[(size_t)n * K + k] = (int8_t)qi;
    sum += qi;
  }
  red[tid] = sum;
  __syncthreads();
  for (int st = 128; st > 0; st >>= 1){
    if (tid < st) red[tid] += red[tid + st];
    __syncthreads();
  }
  if (tid == 0) rs[n] = red[0];
}

// MODE 0: h->gelu-> g min/max atomics only (no store)
// MODE 2: h->gelu-> quantize with g stats -> store int8 (q-128)
// MODE 1: h + bias -> store fp32 out
//
// 128x128 tile, BK=64, mfma_i32_32x32x32_i8, 4 waves each 64x64 (2x2 of 32x32).
// Double-buffered LDS (2 x (A 8K + B 8K) = 32KB), ONE barrier per K-tile:
//   barrier (drains this tile's DMA) -> ds_read frags to regs ->
//   issue DMA for tile k+1 into other buf -> MFMAs.
// DMA source: each GLD16 covers 16 rows x one full aligned 64B line (K%64==0)
// -> 16 fully-used cache lines per instruction (round-3 had 32 half-used).
// LDS layout [row][64B] with XOR chunk swizzle slot = c ^ ((row>>1)&3), applied
// on the DMA *source* side -> fragment ds_read_b128 stays at the b128 BW floor.
template<int MODE>
__global__ __launch_bounds__(256) void gemm_i8(
    const int8_t* __restrict__ A, const int8_t* __restrict__ Bm,
    const int* __restrict__ rowsum, const float* __restrict__ bias,
    void* __restrict__ Cout, int M, int N, int K,
    unsigned* __restrict__ sc)
{
  __shared__ __align__(16) int8_t lds[2][16384];   // per buf: A @0, B @8192

  const int tid  = threadIdx.x;
  const int lane = tid & 63;
  const int wave = tid >> 6;
  const int l31  = lane & 31;
  const int kh   = lane >> 5;          // 0/1 : which 16B half of a 32-k block
  const int n0   = blockIdx.x * 128;
  const int m0   = blockIdx.y * 128;
  const int wm   = (wave & 1) * 64;
  const int wn   = (wave >> 1) * 64;

  // ---- staging source offsets: wave w stages tile rows [32w,32w+32), 2 instrs
  // of 16 rows each, per operand. lane L -> row rbase+(L>>2), LDS slot L&3,
  // source chunk (L&3)^((row>>1)&3)  (XOR swizzle, contiguous 64B per row).
  int aoffs[2], boffs[2];
  const int ldst[2] = { wave * 2048, wave * 2048 + 1024 };
#pragma unroll
  for (int t = 0; t < 2; t++){
    int rowl = wave * 32 + t * 16 + (lane >> 2);       // local tile row 0..127
    int csw  = ((lane & 3) ^ ((rowl >> 1) & 3)) << 4;  // swizzled source chunk
    int ga = m0 + rowl; if (ga >= M) ga = M - 1;
    aoffs[t] = ga * K + csw;
    boffs[t] = (n0 + rowl) * K + csw;
  }

  // ---- fragment read constants: lane reads local row (wm|wn)+mi*32+l31,
  // slot s = (kk*2+kh) ^ ((l31>>1)&3)  (row base mult of 32 -> drops out)
  const int w2  = (l31 >> 1) & 3;
  const int sA0 = (kh ^ w2) << 4;                      // kk=0 slot byte offset
  int arow[2], brow[2];
#pragma unroll
  for (int mi = 0; mi < 2; mi++){
    arow[mi] = (wm + mi * 32 + l31) * 64;
    brow[mi] = (wn + mi * 32 + l31) * 64;
  }

  v16i acc[2][2] = {};
  const int NT = K >> 6;

  // prologue: stage tile 0 into buf 0
#pragma unroll
  for (int t = 0; t < 2; t++){
    GLD16(A  + aoffs[t],        &lds[0][ldst[t]]);
    GLD16(Bm + boffs[t],        &lds[0][8192 + ldst[t]]);
  }

  for (int kt = 0; kt < NT; kt++){
    const int8_t* buf = lds[kt & 1];
    __syncthreads();     // drains vmcnt(0): this buf's DMA (only outstanding);
                         // all waves past reads of this buf from 2 tiles ago
    v4i af[2][2], bf[2][2];          // [kk][mi]
#pragma unroll
    for (int kk = 0; kk < 2; kk++){
      const int sb = sA0 ^ (kk << 5); // (kk*2 xor) -> byte offset flips bit 5
#pragma unroll
      for (int mi = 0; mi < 2; mi++){
        af[kk][mi] = *(const v4i*)(buf + arow[mi] + sb);
        bf[kk][mi] = *(const v4i*)(buf + 8192 + brow[mi] + sb);
      }
    }
    __builtin_amdgcn_sched_barrier(0);   // keep DMA issue after the ds_reads
    if (kt + 1 < NT){
      int8_t* nbuf = lds[(kt + 1) & 1];
      const int ko = (kt + 1) << 6;
#pragma unroll
      for (int t = 0; t < 2; t++){
        GLD16(A  + aoffs[t] + ko, nbuf + ldst[t]);
        GLD16(Bm + boffs[t] + ko, nbuf + 8192 + ldst[t]);
      }
    }
#pragma unroll
    for (int kk = 0; kk < 2; kk++)
#pragma unroll
      for (int mi = 0; mi < 2; mi++)
#pragma unroll
        for (int nj = 0; nj < 2; nj++)
          acc[mi][nj] = __builtin_amdgcn_mfma_i32_32x32x32_i8(af[kk][mi], bf[kk][nj], acc[mi][nj], 0, 0, 0);
  }

  // epilogue scalars
  float s_h, off_h;
  if constexpr (MODE == 1){
    float gmin = dec_f(sc[4]), gmax = dec_f(sc[5]);
    float sg = fmaxf(gmax - gmin, 1e-8f) / 255.0f;
    float zp = rintf(-gmin / sg);
    float sw = fmaxf(__uint_as_float(sc[3]), 1e-8f) / 127.0f;
    s_h = sg * sw; off_h = 128.0f - zp;
  } else {
    float xmin = dec_f(sc[0]), xmax = dec_f(sc[1]);
    float sx = fmaxf(xmax - xmin, 1e-8f) / 255.0f;
    float zp = rintf(-xmin / sx);
    float sw = fmaxf(__uint_as_float(sc[2]), 1e-8f) / 127.0f;
    s_h = sx * sw; off_h = 128.0f - zp;
  }
  float qs = 1.0f, qzp = 0.0f;
  if constexpr (MODE == 2){
    float gmin = dec_f(sc[4]), gmax = dec_f(sc[5]);
    qs = fmaxf(gmax - gmin, 1e-8f) / 255.0f;
    qzp = rintf(-gmin / qs);
  }

  // C/D 32x32 layout: col = lane&31, row = (reg&3) + 8*(reg>>2) + 4*(lane>>5)
  float lmin = 3.4e38f, lmax = -3.4e38f;
#pragma unroll
  for (int nj = 0; nj < 2; nj++){
    const int n = n0 + wn + nj * 32 + l31;
    const float rsv = off_h * (float)rowsum[n];
    const float bv = bias[n];
#pragma unroll
    for (int mi = 0; mi < 2; mi++){
      const int mbase = m0 + wm + mi * 32 + 4 * kh;
#pragma unroll
      for (int r = 0; r < 16; r++){
        const int m = mbase + (r & 3) + 8 * (r >> 2);
        if (m < M){
          float h = s_h * ((float)acc[mi][nj][r] + rsv) + bv;
          if constexpr (MODE == 0){
            float gv = int_gelu_f(h);
            lmin = fminf(lmin, gv); lmax = fmaxf(lmax, gv);
          } else if constexpr (MODE == 2){
            float gv = int_gelu_f(h);
            float qf = fminf(fmaxf(rintf(gv / qs) + qzp, 0.0f), 255.0f);
            ((int8_t*)Cout)[(size_t)m * N + n] = (int8_t)((int)qf - 128);
          } else {
            ((float*)Cout)[(size_t)m * N + n] = h;
          }
        }
      }
    }
  }

  if constexpr (MODE == 0){
    __syncthreads();                   // all waves done with LDS -> reuse as scratch
    float* redA = (float*)&lds[0][0];
    float* redB = ((float*)&lds[0][0]) + 256;
    redA[tid] = lmin; redB[tid] = lmax;
    __syncthreads();
    for (int st = 128; st > 0; st >>= 1){
      if (tid < st){
        redA[tid] = fminf(redA[tid], redA[tid + st]);
        redB[tid] = fmaxf(redB[tid], redB[tid + st]);
      }
      __syncthreads();
    }
    if (tid == 0){
      atomicMin(&sc[4], enc_f(redA[0]));
      atomicMax(&sc[5], enc_f(redB[0]));
    }
  }
}

extern "C" void kernel_launch(void* const* d_in, const int* in_sizes, int n_in,
                              void* d_out, int out_size, void* d_ws, size_t ws_size,
                              hipStream_t stream)
{
  const float* x  = (const float*)d_in[0];
  const float* w1 = (const float*)d_in[1];
  const float* b1 = (const float*)d_in[2];
  const float* w2 = (const float*)d_in[3];
  const float* b2 = (const float*)d_in[4];
  float* out = (float*)d_out;

  const int H = in_sizes[2];            // 3072
  const int D = in_sizes[4];            // 768
  const int M = in_sizes[0] / D;        // 12608

  char* ws = (char*)d_ws;
  unsigned* sc = (unsigned*)ws;
  size_t off = 256;
  int8_t* qx  = (int8_t*)(ws + off); off += (size_t)M * D;   // 9.68 MB
  int8_t* qw1 = (int8_t*)(ws + off); off += (size_t)H * D;   // 2.36 MB
  int8_t* qw2 = (int8_t*)(ws + off); off += (size_t)D * H;   // 2.36 MB
  int* rs1 = (int*)(ws + off); off += (size_t)H * 4;
  int* rs2 = (int*)(ws + off); off += 4096;
  int8_t* qg  = (int8_t*)(ws + off); off += (size_t)M * H;   // 38.7 MB
  (void)ws_size; (void)n_in; (void)out_size;

  init_scalars<<<dim3(1), dim3(64), 0, stream>>>(sc);

  reduce_stats<<<dim3(1280), dim3(256), 0, stream>>>(
      (const float4*)x, M * D / 4,
      (const float4*)w1, H * D / 4,
      (const float4*)w2, D * H / 4, sc);

  quant_act<<<dim3(2048), dim3(256), 0, stream>>>(
      (const float4*)x, (unsigned*)qx, (long)M * D / 4, sc, 0);

  quant_w<<<dim3(H + D), dim3(256), 0, stream>>>(
      w1, w2, qw1, qw2, rs1, rs2, sc, H, D, H);

  // GEMM1 pass A: g min/max only
  gemm_i8<0><<<dim3(H / 128, (M + 127) / 128), dim3(256), 0, stream>>>(
      qx, qw1, rs1, b1, nullptr, M, H, D, sc);

  // GEMM1 pass B: recompute, quantize g -> qg (int8, q-128)
  gemm_i8<2><<<dim3(H / 128, (M + 127) / 128), dim3(256), 0, stream>>>(
      qx, qw1, rs1, b1, qg, M, H, D, sc);

  // GEMM2: out = qg @ qw2^T + b2
  gemm_i8<1><<<dim3(D / 128, (M + 127) / 128), dim3(256), 0, stream>>>(
      qg, qw2, rs2, b2, out, M, D, H, sc);
}

// Round 5
// 354.010 us; speedup vs baseline: 1.8319x; 1.0623x over previous
//
#include <hip/hip_runtime.h>
#include <stdint.h>
#include <stddef.h>

typedef int v4i  __attribute__((ext_vector_type(4)));
typedef int v16i __attribute__((ext_vector_type(16)));

#define GELU_A   (-0.2888f)
#define GELU_B   (-1.769f)
#define INV_SQRT2 0.70710678118654752440f

// async 16B global->LDS (lane i's 16B lands at ldsbase + i*16; ldsbase wave-uniform)
#define GLD16(gp, lp) __builtin_amdgcn_global_load_lds( \
    (const __attribute__((address_space(1))) unsigned int*)(gp), \
    (__attribute__((address_space(3))) unsigned int*)(lp), 16, 0, 0)

// gfx9 s_waitcnt immediates: vmcnt[3:0]=bits3:0, expcnt=bits6:4, lgkmcnt=bits11:8
#define WAIT_VM4 0x0F74   // vmcnt(4), lgkm/exp don't-care
#define WAIT_VM0 0x0F70   // vmcnt(0), lgkm/exp don't-care

// ---- order-preserving float<->uint encoding for atomic min/max ----
__device__ __forceinline__ unsigned enc_f(float f){
  unsigned u = __float_as_uint(f);
  return (u & 0x80000000u) ? ~u : (u | 0x80000000u);
}
__device__ __forceinline__ float dec_f(unsigned e){
  unsigned u = (e & 0x80000000u) ? (e & 0x7FFFFFFFu) : ~e;
  return __uint_as_float(u);
}

__device__ __forceinline__ float int_gelu_f(float x){
  float t = x * INV_SQRT2;
  float at = fminf(fabsf(t), 1.769f);
  float u = at + GELU_B;                 // in [-1.769, 0]
  float p = GELU_A * (u * u) + 1.0f;
  float L = (t > 0.0f) ? p : ((t < 0.0f) ? -p : 0.0f);
  return x * 0.5f * (1.0f + L);
}

// scalar slots: 0 enc(xmin), 1 enc(xmax), 2 bits(absmax w1), 3 bits(absmax w2),
//               4 enc(gmin), 5 enc(gmax)
__global__ void init_scalars(unsigned* sc){
  if (threadIdx.x == 0){
    sc[0] = 0xFFFFFFFFu;
    sc[1] = 0u;
    sc[2] = 0u;
    sc[3] = 0u;
    sc[4] = 0xFFFFFFFFu;
    sc[5] = 0u;
  }
}

// blocks [0,1024): x min/max; [1024,1152): absmax w1 -> slot2; [1152,1280): absmax w2 -> slot3
__global__ __launch_bounds__(256) void reduce_stats(
    const float4* __restrict__ x, int nx4,
    const float4* __restrict__ w1, int n14,
    const float4* __restrict__ w2, int n24,
    unsigned* __restrict__ sc)
{
  __shared__ float ra[256], rb[256];
  const int tid = threadIdx.x;
  const int b = blockIdx.x;
  if (b < 1024){
    float lmin = 3.4e38f, lmax = -3.4e38f;
    for (long i = (long)b * 256 + tid; i < nx4; i += 1024L * 256L){
      float4 v = x[i];
      lmin = fminf(lmin, fminf(fminf(v.x, v.y), fminf(v.z, v.w)));
      lmax = fmaxf(lmax, fmaxf(fmaxf(v.x, v.y), fmaxf(v.z, v.w)));
    }
    ra[tid] = lmin; rb[tid] = lmax;
    __syncthreads();
    for (int s = 128; s > 0; s >>= 1){
      if (tid < s){ ra[tid] = fminf(ra[tid], ra[tid + s]); rb[tid] = fmaxf(rb[tid], rb[tid + s]); }
      __syncthreads();
    }
    if (tid == 0){
      atomicMin(&sc[0], enc_f(ra[0]));
      atomicMax(&sc[1], enc_f(rb[0]));
    }
  } else {
    const float4* w; int n4; int slot; int bl;
    if (b < 1152){ w = w1; n4 = n14; slot = 2; bl = b - 1024; }
    else         { w = w2; n4 = n24; slot = 3; bl = b - 1152; }
    float la = 0.0f;
    for (long i = (long)bl * 256 + tid; i < n4; i += 128L * 256L){
      float4 v = w[i];
      la = fmaxf(la, fmaxf(fmaxf(fabsf(v.x), fabsf(v.y)), fmaxf(fabsf(v.z), fabsf(v.w))));
    }
    ra[tid] = la;
    __syncthreads();
    for (int s = 128; s > 0; s >>= 1){
      if (tid < s) ra[tid] = fmaxf(ra[tid], ra[tid + s]);
      __syncthreads();
    }
    if (tid == 0) atomicMax(&sc[slot], __float_as_uint(ra[0]));
  }
}

// per-tensor asymmetric uint8 fake-quant of activations, stored as (q-128) int8
__global__ __launch_bounds__(256) void quant_act(
    const float4* __restrict__ in, unsigned* __restrict__ out, long n4,
    const unsigned* __restrict__ sc, int slot)
{
  const float vmin = dec_f(sc[slot]);
  const float vmax = dec_f(sc[slot + 1]);
  const float s  = fmaxf(vmax - vmin, 1e-8f) / 255.0f;
  const float zp = rintf(-vmin / s);
  const long stride = (long)gridDim.x * blockDim.x;
  for (long i = (long)blockIdx.x * blockDim.x + threadIdx.x; i < n4; i += stride){
    float4 v = in[i];
    int q0 = (int)fminf(fmaxf(rintf(v.x / s) + zp, 0.0f), 255.0f) - 128;
    int q1 = (int)fminf(fmaxf(rintf(v.y / s) + zp, 0.0f), 255.0f) - 128;
    int q2 = (int)fminf(fmaxf(rintf(v.z / s) + zp, 0.0f), 255.0f) - 128;
    int q3 = (int)fminf(fmaxf(rintf(v.w / s) + zp, 0.0f), 255.0f) - 128;
    out[i] = ((unsigned)(q0 & 255)) | ((unsigned)(q1 & 255) << 8) |
             ((unsigned)(q2 & 255) << 16) | ((unsigned)(q3 & 255) << 24);
  }
}

// per-tensor symmetric int8 weight fake-quant; one block per row; also row sums
__global__ __launch_bounds__(256) void quant_w(
    const float* __restrict__ w1, const float* __restrict__ w2,
    int8_t* __restrict__ qw1, int8_t* __restrict__ qw2,
    int* __restrict__ rs1, int* __restrict__ rs2,
    const unsigned* __restrict__ sc, int n1, int k1, int k2)
{
  __shared__ int red[256];
  const int b = blockIdx.x, tid = threadIdx.x;
  const float* w; int8_t* q; int* rs; int K; int n; float s;
  if (b < n1){ w = w1; q = qw1; rs = rs1; K = k1; n = b;
               s = fmaxf(__uint_as_float(sc[2]), 1e-8f) / 127.0f; }
  else       { w = w2; q = qw2; rs = rs2; K = k2; n = b - n1;
               s = fmaxf(__uint_as_float(sc[3]), 1e-8f) / 127.0f; }
  int sum = 0;
  for (int k = tid; k < K; k += 256){
    float v = w[(size_t)n * K + k];
    float qf = fminf(fmaxf(rintf(v / s), -128.0f), 127.0f);
    int qi = (int)qf;
    q[(size_t)n * K + k] = (int8_t)qi;
    sum += qi;
  }
  red[tid] = sum;
  __syncthreads();
  for (int st = 128; st > 0; st >>= 1){
    if (tid < st) red[tid] += red[tid + st];
    __syncthreads();
  }
  if (tid == 0) rs[n] = red[0];
}

// MODE 0: h->gelu-> g min/max atomics only (no store)
// MODE 2: h->gelu-> quantize with g stats -> store int8 (q-128)
// MODE 1: h + bias -> store fp32 out
//
// 128x128 tile, BK=64, mfma_i32_32x32x32_i8, 4 waves each 64x64 (2x2 of 32x32).
// 3-stage software pipeline, 3 LDS buffers (48KB -> 3 blocks/CU):
//   iter kt: s_waitcnt vmcnt(4)  [own tile-kt DMAs done; kt+1's 4 stay in flight]
//            raw s_barrier        [=> ALL waves' tile-kt DMAs done (each drained
//                                  its own before the barrier); all waves done
//                                  reading tile kt-1 -> its buffer reusable]
//            ds_read tile-kt frags; issue DMA tile kt+2 -> buf[(kt+2)%3]; MFMAs.
// Never vmcnt(0) in steady state -- the prefetch flies across a full iteration.
// DMA source: each GLD16 = 16 rows x one full aligned 64B line. LDS [row][64B]
// with XOR chunk swizzle (source side) keeps frag ds_read_b128 conflict-cheap.
template<int MODE>
__global__ __launch_bounds__(256) void gemm_i8(
    const int8_t* __restrict__ A, const int8_t* __restrict__ Bm,
    const int* __restrict__ rowsum, const float* __restrict__ bias,
    void* __restrict__ Cout, int M, int N, int K,
    unsigned* __restrict__ sc)
{
  __shared__ __align__(16) int8_t lds[3][16384];   // per buf: A @0, B @8192

  const int tid  = threadIdx.x;
  const int lane = tid & 63;
  const int wave = tid >> 6;
  const int l31  = lane & 31;
  const int kh   = lane >> 5;          // 0/1 : which 16B half of a 32-k block
  const int n0   = blockIdx.x * 128;
  const int m0   = blockIdx.y * 128;
  const int wm   = (wave & 1) * 64;
  const int wn   = (wave >> 1) * 64;

  // ---- staging source offsets: wave w stages tile rows [32w,32w+32), 2 instrs
  // of 16 rows each, per operand. lane L -> row rbase+(L>>2), LDS slot L&3,
  // source chunk (L&3)^((row>>1)&3)  (XOR swizzle, contiguous 64B per row).
  int aoffs[2], boffs[2];
  const int ldst[2] = { wave * 2048, wave * 2048 + 1024 };
#pragma unroll
  for (int t = 0; t < 2; t++){
    int rowl = wave * 32 + t * 16 + (lane >> 2);       // local tile row 0..127
    int csw  = ((lane & 3) ^ ((rowl >> 1) & 3)) << 4;  // swizzled source chunk
    int ga = m0 + rowl; if (ga >= M) ga = M - 1;
    aoffs[t] = ga * K + csw;
    boffs[t] = (n0 + rowl) * K + csw;
  }

  // ---- fragment read constants: lane reads local row (wm|wn)+mi*32+l31,
  // slot s = (kk*2+kh) ^ ((l31>>1)&3)  (row base mult of 32 -> drops out)
  const int w2  = (l31 >> 1) & 3;
  const int sA0 = (kh ^ w2) << 4;                      // kk=0 slot byte offset
  int arow[2], brow[2];
#pragma unroll
  for (int mi = 0; mi < 2; mi++){
    arow[mi] = (wm + mi * 32 + l31) * 64;
    brow[mi] = (wn + mi * 32 + l31) * 64;
  }

  v16i acc[2][2] = {};
  const int NT = K >> 6;

  // prologue: stage tiles 0,1 into bufs 0,1 (issue order = vmcnt order)
#pragma unroll
  for (int t = 0; t < 2; t++){
    GLD16(A  + aoffs[t],      &lds[0][ldst[t]]);
    GLD16(Bm + boffs[t],      &lds[0][8192 + ldst[t]]);
  }
#pragma unroll
  for (int t = 0; t < 2; t++){
    GLD16(A  + aoffs[t] + 64, &lds[1][ldst[t]]);
    GLD16(Bm + boffs[t] + 64, &lds[1][8192 + ldst[t]]);
  }

  for (int kt = 0; kt < NT; kt++){
    const int8_t* buf = lds[kt % 3];
    // own tile-kt DMAs are the oldest 4 outstanding -> vmcnt(4); last iter: 0
    if (kt + 1 < NT) __builtin_amdgcn_s_waitcnt(WAIT_VM4);
    else             __builtin_amdgcn_s_waitcnt(WAIT_VM0);
    __builtin_amdgcn_s_barrier();          // raw: no compiler vmcnt(0) fence
    __builtin_amdgcn_sched_barrier(0);     // nothing (esp. next DMA) crosses up

    v4i af[2][2], bf[2][2];                // [kk][mi]
#pragma unroll
    for (int kk = 0; kk < 2; kk++){
      const int sb = sA0 ^ (kk << 5);
#pragma unroll
      for (int mi = 0; mi < 2; mi++){
        af[kk][mi] = *(const v4i*)(buf + arow[mi] + sb);
        bf[kk][mi] = *(const v4i*)(buf + 8192 + brow[mi] + sb);
      }
    }

    if (kt + 2 < NT){                      // prefetch distance 2
      int8_t* nbuf = lds[(kt + 2) % 3];
      const int ko = (kt + 2) << 6;
#pragma unroll
      for (int t = 0; t < 2; t++){
        GLD16(A  + aoffs[t] + ko, nbuf + ldst[t]);
        GLD16(Bm + boffs[t] + ko, nbuf + 8192 + ldst[t]);
      }
    }

#pragma unroll
    for (int kk = 0; kk < 2; kk++)
#pragma unroll
      for (int mi = 0; mi < 2; mi++)
#pragma unroll
        for (int nj = 0; nj < 2; nj++)
          acc[mi][nj] = __builtin_amdgcn_mfma_i32_32x32x32_i8(af[kk][mi], bf[kk][nj], acc[mi][nj], 0, 0, 0);
  }

  // epilogue scalars
  float s_h, off_h;
  if constexpr (MODE == 1){
    float gmin = dec_f(sc[4]), gmax = dec_f(sc[5]);
    float sg = fmaxf(gmax - gmin, 1e-8f) / 255.0f;
    float zp = rintf(-gmin / sg);
    float sw = fmaxf(__uint_as_float(sc[3]), 1e-8f) / 127.0f;
    s_h = sg * sw; off_h = 128.0f - zp;
  } else {
    float xmin = dec_f(sc[0]), xmax = dec_f(sc[1]);
    float sx = fmaxf(xmax - xmin, 1e-8f) / 255.0f;
    float zp = rintf(-xmin / sx);
    float sw = fmaxf(__uint_as_float(sc[2]), 1e-8f) / 127.0f;
    s_h = sx * sw; off_h = 128.0f - zp;
  }
  float qs = 1.0f, qzp = 0.0f;
  if constexpr (MODE == 2){
    float gmin = dec_f(sc[4]), gmax = dec_f(sc[5]);
    qs = fmaxf(gmax - gmin, 1e-8f) / 255.0f;
    qzp = rintf(-gmin / qs);
  }

  // C/D 32x32 layout: col = lane&31, row = (reg&3) + 8*(reg>>2) + 4*(lane>>5)
  float lmin = 3.4e38f, lmax = -3.4e38f;
#pragma unroll
  for (int nj = 0; nj < 2; nj++){
    const int n = n0 + wn + nj * 32 + l31;
    const float rsv = off_h * (float)rowsum[n];
    const float bv = bias[n];
#pragma unroll
    for (int mi = 0; mi < 2; mi++){
      const int mbase = m0 + wm + mi * 32 + 4 * kh;
#pragma unroll
      for (int r = 0; r < 16; r++){
        const int m = mbase + (r & 3) + 8 * (r >> 2);
        if (m < M){
          float h = s_h * ((float)acc[mi][nj][r] + rsv) + bv;
          if constexpr (MODE == 0){
            float gv = int_gelu_f(h);
            lmin = fminf(lmin, gv); lmax = fmaxf(lmax, gv);
          } else if constexpr (MODE == 2){
            float gv = int_gelu_f(h);
            float qf = fminf(fmaxf(rintf(gv / qs) + qzp, 0.0f), 255.0f);
            ((int8_t*)Cout)[(size_t)m * N + n] = (int8_t)((int)qf - 128);
          } else {
            ((float*)Cout)[(size_t)m * N + n] = h;
          }
        }
      }
    }
  }

  if constexpr (MODE == 0){
    __syncthreads();                   // all waves done with LDS -> reuse as scratch
    float* redA = (float*)&lds[0][0];
    float* redB = ((float*)&lds[0][0]) + 256;
    redA[tid] = lmin; redB[tid] = lmax;
    __syncthreads();
    for (int st = 128; st > 0; st >>= 1){
      if (tid < st){
        redA[tid] = fminf(redA[tid], redA[tid + st]);
        redB[tid] = fmaxf(redB[tid], redB[tid + st]);
      }
      __syncthreads();
    }
    if (tid == 0){
      atomicMin(&sc[4], enc_f(redA[0]));
      atomicMax(&sc[5], enc_f(redB[0]));
    }
  }
}

extern "C" void kernel_launch(void* const* d_in, const int* in_sizes, int n_in,
                              void* d_out, int out_size, void* d_ws, size_t ws_size,
                              hipStream_t stream)
{
  const float* x  = (const float*)d_in[0];
  const float* w1 = (const float*)d_in[1];
  const float* b1 = (const float*)d_in[2];
  const float* w2 = (const float*)d_in[3];
  const float* b2 = (const float*)d_in[4];
  float* out = (float*)d_out;

  const int H = in_sizes[2];            // 3072
  const int D = in_sizes[4];            // 768
  const int M = in_sizes[0] / D;        // 12608

  char* ws = (char*)d_ws;
  unsigned* sc = (unsigned*)ws;
  size_t off = 256;
  int8_t* qx  = (int8_t*)(ws + off); off += (size_t)M * D;   // 9.68 MB
  int8_t* qw1 = (int8_t*)(ws + off); off += (size_t)H * D;   // 2.36 MB
  int8_t* qw2 = (int8_t*)(ws + off); off += (size_t)D * H;   // 2.36 MB
  int* rs1 = (int*)(ws + off); off += (size_t)H * 4;
  int* rs2 = (int*)(ws + off); off += 4096;
  int8_t* qg  = (int8_t*)(ws + off); off += (size_t)M * H;   // 38.7 MB
  (void)ws_size; (void)n_in; (void)out_size;

  init_scalars<<<dim3(1), dim3(64), 0, stream>>>(sc);

  reduce_stats<<<dim3(1280), dim3(256), 0, stream>>>(
      (const float4*)x, M * D / 4,
      (const float4*)w1, H * D / 4,
      (const float4*)w2, D * H / 4, sc);

  quant_act<<<dim3(2048), dim3(256), 0, stream>>>(
      (const float4*)x, (unsigned*)qx, (long)M * D / 4, sc, 0);

  quant_w<<<dim3(H + D), dim3(256), 0, stream>>>(
      w1, w2, qw1, qw2, rs1, rs2, sc, H, D, H);

  // GEMM1 pass A: g min/max only
  gemm_i8<0><<<dim3(H / 128, (M + 127) / 128), dim3(256), 0, stream>>>(
      qx, qw1, rs1, b1, nullptr, M, H, D, sc);

  // GEMM1 pass B: recompute, quantize g -> qg (int8, q-128)
  gemm_i8<2><<<dim3(H / 128, (M + 127) / 128), dim3(256), 0, stream>>>(
      qx, qw1, rs1, b1, qg, M, H, D, sc);

  // GEMM2: out = qg @ qw2^T + b2
  gemm_i8<1><<<dim3(D / 128, (M + 127) / 128), dim3(256), 0, stream>>>(
      qg, qw2, rs2, b2, out, M, D, H, sc);
}